// Round 7
// baseline (2017.643 us; speedup 1.0000x reference)
//
#include <hip/hip_runtime.h>
#include <math.h>

#define NN 325
#define BB 32
#define NB (NN*BB)            // 10400
#define TENC 6
#define TDEC 12
#define WSET 65472            // fp32 Weff: Wzr(340x128)+Wc(340x64)+bzr(128)+bc(64)
#define WT_SET (192*352)      // f16 transposed weights per set
#define M_SET (325*192)       // Mzr[325][128] + Mc[325][64]
#define G16_MAT (384*352)
#define PT_B 765952ull        // 2176*352 f16 per buf
#define PT_E 1531904ull       // 2 bufs per stream
#define AST 356               // Aproj LDS row stride (f16), conflict-free

typedef _Float16 f16;
typedef f16 f16x4 __attribute__((ext_vector_type(4)));
typedef f16 f16x8 __attribute__((ext_vector_type(8)));
typedef float f32x4 __attribute__((ext_vector_type(4)));

static constexpr float ALPHA = 0.05f;
static constexpr float BETA  = 0.95f;
static constexpr float GAMMA = 0.95f;
static constexpr float ISQ2  = 0.7071067811865476f;

// ---------------- workspace offsets (floats) ----------------
static constexpr size_t OFF_G    = 0;                        // 211250
static constexpr size_t OFF_RS   = OFF_G + 2ull*NN*NN;       // 650
static constexpr size_t OFF_RV   = OFF_RS + 650;             // 1300
static constexpr size_t OFF_WEFF = OFF_RV + 1300;            // 3*WSET
static constexpr size_t OFF_WT   = OFF_WEFF + 3ull*WSET;
static constexpr size_t OFF_G16  = OFF_WT + (3ull*WT_SET)/2;
static constexpr size_t OFF_M    = OFF_G16 + (4ull*G16_MAT)/2;
static constexpr size_t OFF_TV   = OFF_M + 3ull*M_SET;       // 576
static constexpr size_t OFF_XS   = OFF_TV + 576;             // 249600 f16 -> /2
static constexpr size_t OFF_PT   = OFF_XS + (2ull*TENC*NB*4)/2;  // 2*PT_E f16
static constexpr size_t OFF_ZR   = OFF_PT + (2ull*PT_E)/2;       // 2*NB*64 fp32 (G2 alias)
static constexpr size_t OFF_HENC = OFF_ZR + 2ull*NB*64;
static constexpr size_t OFF_HDEC = OFF_HENC + 2ull*NB*64;
static constexpr size_t OFF_YS   = OFF_HDEC + (size_t)NB*64;

__device__ inline unsigned pk2(float a, float b) {
    union { f16 h[2]; unsigned u; } x;
    x.h[0] = (f16)a; x.h[1] = (f16)b; return x.u;
}
__device__ inline unsigned pk2h(f16 a, f16 b) {
    union { f16 h[2]; unsigned u; } x;
    x.h[0] = a; x.h[1] = b; return x.u;
}
__device__ inline void st4h(f16* p, float a, float b, float c, float d) {
    f16x4 v; v[0]=(f16)a; v[1]=(f16)b; v[2]=(f16)c; v[3]=(f16)d;
    *(f16x4*)p = v;
}
__device__ inline f16x8 ld8_lds(const f16* p) {
    f16x4 lo = *(const f16x4*)p;
    f16x4 hi = *(const f16x4*)(p + 4);
    f16x8 r;
    r[0]=lo[0]; r[1]=lo[1]; r[2]=lo[2]; r[3]=lo[3];
    r[4]=hi[0]; r[5]=hi[1]; r[6]=hi[2]; r[7]=hi[3];
    return r;
}

// ---------------- prep ----------------
__global__ void k_sums(const float* __restrict__ adj, float* rs, float* cs) {
    int v = blockIdx.x; int t = threadIdx.x;
    float sr = 0.f, sc = 0.f;
    for (int w = t; w < NN; w += 64) { sr += adj[v*NN + w]; sc += adj[w*NN + v]; }
    for (int o = 32; o > 0; o >>= 1) { sr += __shfl_down(sr, o); sc += __shfl_down(sc, o); }
    if (t == 0) { rs[v] = sr + 1.0f; cs[v] = sc + 1.0f; }
}

__global__ void k_buildG(const float* __restrict__ adj, const float* __restrict__ P,
                         const float* __restrict__ rs, const float* __restrict__ cs,
                         float* __restrict__ G) {
    int idx = blockIdx.x*256 + threadIdx.x;
    if (idx >= NN*NN) return;
    int w = idx / NN, v = idx % NN;
    float d = (v == w) ? 1.0f : 0.0f;
    float a1  = (adj[v*NN + w] + d) / rs[v];
    float a1t = (adj[w*NN + v] + d) / cs[v];
    float p = P[v*NN + w];
    G[idx]         = BETA*a1  + GAMMA*p;   // G_A[n=w][v]
    G[NN*NN + idx] = BETA*a1t + GAMMA*p;   // G_T[n=w][v]
}

__global__ __launch_bounds__(256) void k_gg(const float* __restrict__ G, float* __restrict__ G2) {
    int g = blockIdx.z;
    const float* A = G + (size_t)g*NN*NN;
    float* C = G2 + (size_t)g*NN*NN;
    int n0 = blockIdx.y*32, j0 = blockIdx.x*32;
    int tx = threadIdx.x & 31, ty = threadIdx.x >> 5;
    __shared__ float As[32][33];
    __shared__ float Bs[32][33];
    float acc[4] = {};
    for (int k0 = 0; k0 < NN; k0 += 32) {
        for (int l = threadIdx.x; l < 32*32; l += 256) {
            int i = l >> 5, kk = l & 31;
            int n = n0 + i, k = k0 + kk;
            As[i][kk] = (n < NN && k < NN) ? A[(size_t)n*NN + k] : 0.0f;
            int j = j0 + kk;
            Bs[i][kk] = (k0 + i < NN && j < NN) ? A[(size_t)(k0+i)*NN + j] : 0.0f;
        }
        __syncthreads();
        #pragma unroll 8
        for (int kk = 0; kk < 32; kk++) {
            float bv = Bs[kk][tx];
            #pragma unroll
            for (int i = 0; i < 4; i++) acc[i] = fmaf(As[ty + 8*i][kk], bv, acc[i]);
        }
        __syncthreads();
    }
    #pragma unroll
    for (int i = 0; i < 4; i++) {
        int n = n0 + ty + 8*i, j = j0 + tx;
        if (n < NN && j < NN) C[(size_t)n*NN + j] = acc[i];
    }
}

// G16[m][384][352] f16: m=g*2+s ; s=0: aI+G ; s=1: aI+aG+G2 ; rows n>=NN zero
__global__ void k_g16(const float* __restrict__ G, const float* __restrict__ G2,
                      f16* __restrict__ G16) {
    int idx = blockIdx.x*256 + threadIdx.x;
    if (idx >= 4*G16_MAT) return;
    int m = idx / G16_MAT;
    int rem = idx - m*G16_MAT;
    int n = rem / 352, v = rem - n*352;
    int g = m >> 1, s = m & 1;
    float val = 0.0f;
    if (n < NN && v < NN) {
        float gv = G[(size_t)g*NN*NN + n*NN + v];
        float d = (n == v) ? ALPHA : 0.0f;
        val = (s == 0) ? (gv + d)
                       : (G2[(size_t)g*NN*NN + n*NN + v] + ALPHA*gv + d);
    }
    G16[idx] = (f16)val;
}

__global__ void k_rowsum(const float* __restrict__ G, const float* __restrict__ G2,
                         float* __restrict__ rv) {
    int row = blockIdx.x;
    int g = row / NN, n = row - g*NN;
    int t = threadIdx.x;
    float s1 = 0.f, s2 = 0.f;
    for (int v = t; v < NN; v += 64) {
        s1 += G[(size_t)g*NN*NN + n*NN + v];
        s2 += G2[(size_t)g*NN*NN + n*NN + v];
    }
    for (int o = 32; o > 0; o >>= 1) { s1 += __shfl_down(s1, o); s2 += __shfl_down(s2, o); }
    if (t == 0) {
        rv[(g*2 + 0)*NN + n] = ALPHA + s1;
        rv[(g*2 + 1)*NN + n] = ALPHA + ALPHA*s1 + s2;
    }
}

__global__ void k_weff3(const float* __restrict__ W0, const float* __restrict__ b0,
                        const float* __restrict__ W1, const float* __restrict__ b1,
                        const float* __restrict__ W2, const float* __restrict__ b2,
                        float* __restrict__ WeffAll) {
    int s = blockIdx.y;
    const float* W = (s == 0) ? W0 : (s == 1) ? W1 : W2;
    const float* b = (s == 0) ? b0 : (s == 1) ? b1 : b2;
    float* Wset = WeffAll + (size_t)s*WSET;
    float* Wzr = Wset;
    float* Wc  = Wset + 43520;
    float* bzr = Wset + 65280;
    float* bc  = Wset + 65408;
    int tid = blockIdx.x*256 + threadIdx.x;
    if (tid < 340*192) {
        int k = tid / 192, col = tid % 192;
        int g = col >> 6, oo = col & 63;
        const float* Wa = W + (2*g)*204*64;
        const float* Wb = W + (2*g+1)*204*64;
        float val;
        if (k < 68)       val = Wa[k*64+oo] + Wb[k*64+oo];
        else if (k < 204) val = Wa[k*64+oo];
        else              val = Wb[(k-136)*64+oo];
        if (g < 2) Wzr[k*128 + g*64 + oo] = val;
        else       Wc[k*64 + oo] = val;
    }
    if (blockIdx.x == 0 && threadIdx.x < 192) {
        int col = threadIdx.x, g = col >> 6, oo = col & 63;
        float bv = b[(2*g)*64+oo] + b[(2*g+1)*64+oo];
        if (g < 2) bzr[col] = bv; else bc[oo] = bv;
    }
}

__global__ void k_wt3(const float* __restrict__ WeffAll, f16* __restrict__ WtAll) {
    int s = blockIdx.y;
    const float* Weff = WeffAll + (size_t)s*WSET;
    f16* Wt = WtAll + (size_t)s*WT_SET;
    int idx = blockIdx.x*256 + threadIdx.x;
    if (idx >= 192*352) return;
    int o = idx / 352, k = idx - o*352;
    float v = 0.0f;
    if (k < 340) {
        int p = k / 68, c = k - p*68;
        if (c != 3) v = (o < 128) ? Weff[k*128 + o] : Weff[43520 + k*64 + (o - 128)];
    }
    Wt[idx] = (f16)v;
}

__global__ void k_M3(const float* __restrict__ WeffAll, const float* __restrict__ rv,
                     float* __restrict__ MAll) {
    int s = blockIdx.y;
    const float* Weff = WeffAll + (size_t)s*WSET;
    float* M = MAll + (size_t)s*M_SET;
    int idx = blockIdx.x*256 + threadIdx.x;
    if (idx >= 325*192) return;
    int n = idx / 192, q = idx - n*192;
    float acc;
    if (q < 128) {
        int o = q;
        acc = Weff[3*128 + o];
        #pragma unroll
        for (int p = 1; p <= 4; p++)
            acc += rv[(p-1)*NN + n] * Weff[(p*68 + 3)*128 + o];
        M[(size_t)n*128 + o] = acc;
    } else {
        int o = q - 128;
        acc = Weff[43520 + 3*64 + o];
        #pragma unroll
        for (int p = 1; p <= 4; p++)
            acc += rv[(p-1)*NN + n] * Weff[43520 + (p*68 + 3)*64 + o];
        M[325*128 + (size_t)n*64 + o] = acc;
    }
}

__global__ void k_tv(const float* __restrict__ st, float* __restrict__ tv) {
    int idx = blockIdx.x*256 + threadIdx.x;
    if (idx >= 18*32) return;
    int b = idx & 31, t = idx >> 5;
    float v;
    if (t < 6) {
        float hour   = (st[b*48 + 24 + 2*t] + 0.5f) * 23.0f;
        float minute = (st[b*48 + 36 + 2*t] + 0.5f) * 59.0f;
        v = floorf((hour*60.0f + minute) / 5.0f);
    } else {
        int td = t - 6;
        v = floorf((st[b*48 + 24 + td] + 0.5f) * 6.0f);
    }
    tv[idx] = v;
}

__global__ void k_xs16(const float* __restrict__ x, f16* __restrict__ xs) {
    int idx = blockIdx.x*256 + threadIdx.x;
    if (idx >= 2*TENC*NB*4) return;
    int c = idx & 3;
    int r = (idx >> 2) % NB;
    int t = (idx / (4*NB)) % TENC;
    int e = idx / (4*NB*TENC);
    int n = r / BB, b = r % BB;
    float val = 0.0f;
    if (c < 3) {
        float xe = x[((b*3 + c)*NN + n)*12 + 2*t];
        float xo = x[((b*3 + c)*NN + n)*12 + 2*t + 1];
        val = (e == 0) ? (xe - xo)*ISQ2 : (xe + xo)*ISQ2;
    }
    xs[idx] = (f16)val;
}

__global__ void k_initH(const float* __restrict__ H1_0, const float* __restrict__ H2_0,
                        float* __restrict__ Henc) {
    int idx = blockIdx.x*256 + threadIdx.x;
    if (idx >= 2*NB*64) return;
    int k = idx & 63;
    int r = (idx >> 6) % NB;
    int e = idx / (NB*64);
    int n = r / BB, b = r % BB;
    const float* src = e ? H2_0 : H1_0;
    Henc[idx] = src[((size_t)b*NN + n)*64 + k];
}

// P0T init: buf0 full values; v-pad (v>=NN) zero in BOTH bufs
__global__ void k_initPT(const f16* __restrict__ xs, const float* __restrict__ H1_0,
                         const float* __restrict__ H2_0, f16* __restrict__ PTb) {
    int idx = blockIdx.x*256 + threadIdx.x;
    if (idx >= 2*2176*352) return;
    int v = idx % 352;
    int j = (idx / 352) % 2176;
    int e = idx / (352*2176);
    f16* P0 = PTb + (size_t)e*PT_E;
    if (v >= NN) {
        P0[(size_t)j*352 + v] = (f16)0.0f;
        P0[PT_B + (size_t)j*352 + v] = (f16)0.0f;
        return;
    }
    int b = j / 68, c = j - b*68;
    f16 val;
    if (c < 3)       val = xs[(size_t)e*TENC*NB*4 + (size_t)(v*32+b)*4 + c];
    else if (c == 3) val = (f16)0.0f;
    else {
        const float* h0 = e ? H2_0 : H1_0;
        val = (f16)h0[((size_t)b*NN + v)*64 + (c-4)];
    }
    P0[(size_t)j*352 + v] = val;
}

// ============ fused half-step: diff (LDS-free) + proj (from LDS Aproj) ============
// Block = 2 nodes = 64 rows, 512 threads (8 waves). Grid (163, E).
// Phase A: Aproj[64][352] = [plane0 | 4 diffused planes] ; one __syncthreads.
// Phase B: MODE 0: 128 outs -> z->ZR, r*H->PTnext. MODE 1: 64 outs -> H update
//          (+xn channels for encoder / +fc for decoder).
template<int MODE, int DEC>
__global__ __launch_bounds__(512) void k_fstep(
    const f16* __restrict__ G16,
    const f16* __restrict__ PTcurB, f16* __restrict__ PTnxtB,
    const f16* __restrict__ WtB, int wt_str,
    const float* __restrict__ biasB, int bias_str,
    const float* __restrict__ MB, int m_str,
    const float* __restrict__ tv,
    float* __restrict__ ZRB, float* __restrict__ HstB,
    const f16* __restrict__ xn0, const f16* __restrict__ xn1,
    const float* __restrict__ Wfc, const float* __restrict__ bfc,
    float* __restrict__ yout)
{
    __shared__ f16 Aproj[64*AST];   // 45568 B
    int e = blockIdx.y;
    const f16* PTc = PTcurB + (size_t)e*PT_E;
    f16* PTn = PTnxtB + (size_t)e*PT_E;
    const f16* Wt = WtB + (size_t)e*wt_str + (MODE ? 128*352 : 0);
    const float* bias = biasB + (size_t)e*bias_str + (MODE ? 65408 : 65280);
    const float* Mp = MB + (size_t)e*m_str + (MODE ? 325*128 : 0);
    float* ZR = ZRB + (size_t)e*NB*64;
    float* Hs = HstB + (size_t)e*NB*64;
    int n0 = blockIdx.x*2;
    int r0 = n0*32;
    int tid = threadIdx.x;
    int lane = tid & 63, w = tid >> 6;
    int l15 = lane & 15, lk = lane >> 4;

    // stage plane0 (cols 0..67, transposed read from PT) + zero K-pad 340..351
    for (int q = tid; q < 64*34; q += 512) {
        int row = q / 34, cp = (q - row*34)*2;
        int b = row & 31, dn = row >> 5;
        f16 v0 = PTc[(size_t)(b*68 + cp)*352 + n0 + dn];
        f16 v1 = PTc[(size_t)(b*68 + cp + 1)*352 + n0 + dn];
        *(unsigned*)(Aproj + row*AST + cp) = pk2h(v0, v1);
    }
    for (int q = tid; q < 64*6; q += 512) {
        int row = q / 6, pr = q - row*6;
        *(unsigned*)(Aproj + row*AST + 340 + pr*2) = 0u;
    }

    // ---- phase A: D^T tiles, B = 16 G16 rows (m = l15>>2, dn = l15&3) in VGPRs ----
    {
        int m = l15 >> 2, dn = l15 & 3;
        int nrow = (dn < 2) ? (n0 + dn) : 383;     // rows >= NN are zero
        const f16* grow = G16 + (size_t)m*G16_MAT + (size_t)nrow*352 + lk*8;
        f16x8 agr[11];
        #pragma unroll
        for (int ks = 0; ks < 11; ks++) agr[ks] = *(const f16x8*)(grow + ks*32);

        const f16* abase = PTc + (size_t)l15*352 + lk*8;
        for (int jt = w; jt < 136; jt += 8) {
            const f16* ap = abase + (size_t)jt*16*352;
            f32x4 acc = {};
            #pragma unroll
            for (int ks = 0; ks < 11; ks++) {
                f16x8 af = *(const f16x8*)(ap + ks*32);
                acc = __builtin_amdgcn_mfma_f32_16x16x32_f16(af, agr[ks], acc, 0,0,0);
            }
            if (dn < 2) {
                int j0r = jt*16 + lk*4;            // 4 consecutive j, same b
                int b = j0r / 68, c = j0r - b*68;
                st4h(Aproj + (dn*32 + b)*AST + (m+1)*68 + c,
                     acc[0], acc[1], acc[2], acc[3]);
            }
        }
    }
    __syncthreads();

    // ---- phase B ----
    if constexpr (MODE == 0) {
        int rg = w >> 2, cg = w & 3;   // 2 row-groups x 4 col-groups
        f32x4 acc[2][2] = {};
        for (int ks = 0; ks < 11; ks++) {
            f16x8 afr[2], bfr[2];
            #pragma unroll
            for (int a = 0; a < 2; a++)
                afr[a] = ld8_lds(Aproj + (rg*32 + a*16 + l15)*AST + ks*32 + lk*8);
            #pragma unroll
            for (int bt = 0; bt < 2; bt++)
                bfr[bt] = *(const f16x8*)(Wt + (size_t)(cg*32 + bt*16 + l15)*352 + ks*32 + lk*8);
            #pragma unroll
            for (int a = 0; a < 2; a++)
                #pragma unroll
                for (int bt = 0; bt < 2; bt++)
                    acc[a][bt] = __builtin_amdgcn_mfma_f32_16x16x32_f16(afr[a], bfr[bt], acc[a][bt], 0,0,0);
        }
        #pragma unroll
        for (int a = 0; a < 2; a++) {
            #pragma unroll
            for (int bt = 0; bt < 2; bt++) {
                int o = cg*32 + bt*16 + l15;
                #pragma unroll
                for (int rr = 0; rr < 4; rr++) {
                    int r = r0 + rg*32 + a*16 + lk*4 + rr;
                    if (r >= NB) continue;
                    int n = r >> 5, b = r & 31;
                    float pre = acc[a][bt][rr] + bias[o] + tv[b]*Mp[(size_t)n*128 + o];
                    float sg = 1.0f / (1.0f + expf(-pre));
                    if (o < 64) {
                        ZR[(size_t)r*64 + o] = sg;
                    } else {
                        int oh = o - 64;
                        float g = sg * Hs[(size_t)r*64 + oh];
                        PTn[(size_t)(b*68 + 4 + oh)*352 + n] = (f16)g;
                    }
                }
            }
        }
        // copy x/t channels cur -> next
        if (tid < 256) {
            int row = tid >> 2, q = tid & 3;
            int b = row & 31, dn = row >> 5, n = n0 + dn;
            if (n < NN) {
                size_t off = (size_t)(b*68 + q)*352 + n;
                PTn[off] = PTc[off];
            }
        }
    } else {
        int rg = w >> 1, cg = w & 1;   // 4 row-groups x 2 col-groups
        f32x4 acc[2] = {};
        for (int ks = 0; ks < 11; ks++) {
            f16x8 afr = ld8_lds(Aproj + (rg*16 + l15)*AST + ks*32 + lk*8);
            #pragma unroll
            for (int bt = 0; bt < 2; bt++) {
                f16x8 bfr = *(const f16x8*)(Wt + (size_t)(cg*32 + bt*16 + l15)*352 + ks*32 + lk*8);
                acc[bt] = __builtin_amdgcn_mfma_f32_16x16x32_f16(afr, bfr, acc[bt], 0,0,0);
            }
        }
        if constexpr (DEC) __syncthreads();   // Aproj reuse as Hl below
        f16* Hl = Aproj;
        #pragma unroll
        for (int bt = 0; bt < 2; bt++) {
            int o = cg*32 + bt*16 + l15;
            #pragma unroll
            for (int rr = 0; rr < 4; rr++) {
                int rl = rg*16 + lk*4 + rr;
                int r = r0 + rl;
                if (r >= NB) continue;
                int n = r >> 5, b = r & 31;
                float pre = acc[bt][rr] + bias[o] + tv[b]*Mp[(size_t)n*64 + o];
                float cv = tanhf(pre);
                float zv = ZR[(size_t)r*64 + o];
                float hv = Hs[(size_t)r*64 + o];
                float hnew = zv*hv + (1.0f - zv)*cv;
                Hs[(size_t)r*64 + o] = hnew;
                PTn[(size_t)(b*68 + 4 + o)*352 + n] = (f16)hnew;
                if (DEC) Hl[rl*68 + o] = (f16)hnew;
            }
        }
        if constexpr (!DEC) {
            const f16* xn = e ? xn1 : xn0;
            if (xn && tid < 256) {
                int row = tid >> 2, q = tid & 3;
                int b = row & 31, dn = row >> 5, n = n0 + dn;
                if (n < NN) {
                    int r = n*32 + b;
                    f16 v = (q < 3) ? xn[(size_t)r*4 + q] : (f16)0.0f;
                    PTn[(size_t)(b*68 + q)*352 + n] = v;
                }
            }
        } else {
            __syncthreads();
            for (int q = tid; q < 192; q += 512) {
                int row = q / 3, o = q - row*3;
                int r = r0 + row;
                if (r < NB) {
                    float a = bfc[o];
                    #pragma unroll 8
                    for (int k = 0; k < 64; k++)
                        a = fmaf((float)Hl[row*68 + k], Wfc[k*3 + o], a);
                    yout[(size_t)r*3 + o] = a;
                    PTn[(size_t)((r & 31)*68 + o)*352 + (r >> 5)] = (f16)a;
                }
            }
            if (tid < 64) {
                int r = r0 + tid;
                if (r < NB) PTn[(size_t)((r & 31)*68 + 3)*352 + (r >> 5)] = (f16)0.0f;
            }
        }
    }
}

// -------- fuse + agg via MFMA; inits decoder P0T buf0 --------
__global__ __launch_bounds__(256) void k_fuse16(const float* __restrict__ H1,
        const float* __restrict__ H2,
        const float* __restrict__ wL, const float* __restrict__ bL,
        const float* __restrict__ wH, const float* __restrict__ bH,
        const float* __restrict__ Wcam, const float* __restrict__ bcam,
        const float* __restrict__ Wagg, const float* __restrict__ bagg,
        float* __restrict__ Hdec, f16* __restrict__ PTn) {
    int r0 = blockIdx.x * 64;
    int tid = threadIdx.x;
    int lane = tid & 63, wave = tid >> 6;
    int wm = wave >> 1, wn = wave & 1;
    int l15 = lane & 15, lk = lane >> 4;
    __shared__ f16 Al[64*264];
    __shared__ f16 Wl[64*264];
    unsigned* La = (unsigned*)Al;
    unsigned* Lw = (unsigned*)Wl;
    for (int l = tid; l < 64*64; l += 256) {
        int i = l >> 6, k = l & 63;
        int r = r0 + i;
        unsigned val = 0;
        if (r < NB) {
            int n = r >> 5;
            float h1 = H1[(size_t)r*64 + k], h2 = H2[(size_t)r*64 + k];
            float s = h1 + h2;
            val = pk2(s*wL[n*64+k] + 2.0f*bL[n*64+k], s*wH[n*64+k] + 2.0f*bH[n*64+k]);
        }
        La[i*132 + k] = val;
    }
    for (int l = tid; l < 64*32; l += 256) {
        int i = l >> 5, kp = l & 31;
        int r = r0 + i;
        unsigned v1 = 0, v2 = 0;
        if (r < NB) {
            float2 a = *(const float2*)(H1 + (size_t)r*64 + 2*kp);
            float2 b = *(const float2*)(H2 + (size_t)r*64 + 2*kp);
            v1 = pk2(a.x, a.y);
            v2 = pk2(b.x, b.y);
        }
        La[i*132 + 64 + kp] = v1;
        La[i*132 + 96 + kp] = v2;
    }
    for (int idx = tid; idx < 64*128; idx += 256) {
        int kp = idx & 63, half = (idx >> 6) & 1, o = idx >> 7;
        if (half == 0) {
            float a = 0.3f * Wcam[(size_t)(2*kp)*64 + o];
            float b = 0.3f * Wcam[(size_t)(2*kp+1)*64 + o];
            Lw[o*132 + kp] = pk2(a, b);
        } else {
            float a = 0.7f * Wagg[(size_t)(2*kp)*64 + o];
            float b = 0.7f * Wagg[(size_t)(2*kp+1)*64 + o];
            Lw[o*132 + 64 + kp] = pk2(a, b);
        }
    }
    __syncthreads();
    f32x4 acc[2][2] = {};
    for (int k0 = 0; k0 < 256; k0 += 32) {
        f16x8 afr[2], bfr[2];
        #pragma unroll
        for (int a = 0; a < 2; a++)
            afr[a] = ld8_lds(Al + (wm*32 + a*16 + l15)*264 + k0 + lk*8);
        #pragma unroll
        for (int b = 0; b < 2; b++)
            bfr[b] = ld8_lds(Wl + (wn*32 + b*16 + l15)*264 + k0 + lk*8);
        #pragma unroll
        for (int a = 0; a < 2; a++)
            #pragma unroll
            for (int b = 0; b < 2; b++)
                acc[a][b] = __builtin_amdgcn_mfma_f32_16x16x32_f16(afr[a], bfr[b], acc[a][b], 0,0,0);
    }
    #pragma unroll
    for (int a = 0; a < 2; a++) {
        #pragma unroll
        for (int b = 0; b < 2; b++) {
            int o = wn*32 + b*16 + l15;
            float bo = 0.3f*bcam[o] + 0.7f*bagg[o];
            #pragma unroll
            for (int rr = 0; rr < 4; rr++) {
                int r = r0 + wm*32 + a*16 + lk*4 + rr;
                if (r >= NB) continue;
                float val = acc[a][b][rr] + bo;
                Hdec[(size_t)r*64 + o] = val;
                PTn[(size_t)((r & 31)*68 + 4 + o)*352 + (r >> 5)] = (f16)val;
            }
        }
    }
    {
        int r = r0 + (tid >> 2), q = tid & 3;
        if (r < NB) PTn[(size_t)((r & 31)*68 + q)*352 + (r >> 5)] = (f16)0.0f;
    }
}

__global__ void k_out(const float* __restrict__ ys, float* __restrict__ out) {
    int idx = blockIdx.x*256 + threadIdx.x;
    if (idx >= BB*3*NN*12) return;
    int l = idx % 12;
    int n = (idx / 12) % NN;
    int o = (idx / (12*NN)) % 3;
    int b = idx / (12*NN*3);
    int q = o*12 + l;
    int t = q / 3, c = q % 3;
    out[idx] = ys[((size_t)t*NB + n*BB + b)*3 + c];
}

// ---------------- host ----------------
extern "C" void kernel_launch(void* const* d_in, const int* in_sizes, int n_in,
                              void* d_out, int out_size, void* d_ws, size_t ws_size,
                              hipStream_t stream) {
    const float* x      = (const float*)d_in[0];
    const float* st     = (const float*)d_in[1];
    const float* adj    = (const float*)d_in[2];
    const float* P      = (const float*)d_in[3];
    const float* H1_0   = (const float*)d_in[4];
    const float* H2_0   = (const float*)d_in[6];
    const float* W_encD = (const float*)d_in[8];
    const float* b_encD = (const float*)d_in[9];
    const float* W_encAD= (const float*)d_in[10];
    const float* b_encAD= (const float*)d_in[11];
    const float* W_dec  = (const float*)d_in[12];
    const float* b_dec  = (const float*)d_in[13];
    const float* W_fc   = (const float*)d_in[14];
    const float* b_fc   = (const float*)d_in[15];
    const float* W_aggH = (const float*)d_in[16];
    const float* b_aggH = (const float*)d_in[17];
    const float* W_camH = (const float*)d_in[20];
    const float* b_camH = (const float*)d_in[21];
    const float* wL     = (const float*)d_in[24];
    const float* bL     = (const float*)d_in[25];
    const float* wH     = (const float*)d_in[26];
    const float* bH     = (const float*)d_in[27];

    float* ws   = (float*)d_ws;
    float* G    = ws + OFF_G;
    float* rs   = ws + OFF_RS;
    float* cs   = rs + NN;
    float* rv   = ws + OFF_RV;
    float* Weff = ws + OFF_WEFF;
    f16*   Wt   = (f16*)(ws + OFF_WT);
    f16*   G16  = (f16*)(ws + OFF_G16);
    float* Mw   = ws + OFF_M;
    float* tv   = ws + OFF_TV;
    f16*   xs   = (f16*)(ws + OFF_XS);
    f16*   PT   = (f16*)(ws + OFF_PT);    // [e][buf][2176][352]
    float* ZR   = ws + OFF_ZR;
    float* G2   = ZR;                      // alias: prep only
    float* Henc = ws + OFF_HENC;
    float* Hdec = ws + OFF_HDEC;
    float* ys   = ws + OFF_YS;

    // ---- prep ----
    k_sums<<<NN, 64, 0, stream>>>(adj, rs, cs);
    k_buildG<<<(NN*NN + 255)/256, 256, 0, stream>>>(adj, P, rs, cs, G);
    k_gg<<<dim3(11,11,2), 256, 0, stream>>>(G, G2);
    k_g16<<<(4*G16_MAT + 255)/256, 256, 0, stream>>>(G, G2, G16);
    k_rowsum<<<650, 64, 0, stream>>>(G, G2, rv);
    k_weff3<<<dim3(255,3), 256, 0, stream>>>(W_encD, b_encD, W_encAD, b_encAD,
                                             W_dec, b_dec, Weff);
    k_wt3<<<dim3((192*352 + 255)/256, 3), 256, 0, stream>>>(Weff, Wt);
    k_M3<<<dim3((325*192 + 255)/256, 3), 256, 0, stream>>>(Weff, rv, Mw);
    k_tv<<<3, 256, 0, stream>>>(st, tv);
    k_xs16<<<(2*TENC*NB*4 + 255)/256, 256, 0, stream>>>(x, xs);
    k_initH<<<(2*NB*64 + 255)/256, 256, 0, stream>>>(H1_0, H2_0, Henc);
    k_initPT<<<(2*2176*352 + 255)/256, 256, 0, stream>>>(xs, H1_0, H2_0, PT);

    int par = 0;
    // ---- encoders (E=2) ----
    for (int t = 0; t < TENC; t++) {
        const f16* xn0 = (t < TENC-1) ? (xs + (size_t)(t+1)*NB*4) : nullptr;
        const f16* xn1 = (t < TENC-1) ? (xs + (size_t)(TENC + t+1)*NB*4) : nullptr;
        k_fstep<0,0><<<dim3(163,2), 512, 0, stream>>>(G16,
            PT + (size_t)par*PT_B, PT + (size_t)(par^1)*PT_B,
            Wt, WT_SET, Weff, WSET, Mw, M_SET, tv + (size_t)t*32,
            ZR, Henc, nullptr, nullptr, nullptr, nullptr, nullptr);
        par ^= 1;
        k_fstep<1,0><<<dim3(163,2), 512, 0, stream>>>(G16,
            PT + (size_t)par*PT_B, PT + (size_t)(par^1)*PT_B,
            Wt, WT_SET, Weff, WSET, Mw, M_SET, tv + (size_t)t*32,
            ZR, Henc, xn0, xn1, nullptr, nullptr, nullptr);
        par ^= 1;
    }

    // ---- fuse + decoder P0T buf0 init (par == 0 here) ----
    k_fuse16<<<163, 256, 0, stream>>>(Henc, Henc + (size_t)NB*64,
                                      wL, bL, wH, bH, W_camH, b_camH, W_aggH, b_aggH,
                                      Hdec, PT);

    // ---- decoder (E=1, weight set 2) ----
    for (int t = 0; t < TDEC; t++) {
        const float* tvt = tv + (size_t)(6 + t)*32;
        k_fstep<0,0><<<dim3(163,1), 512, 0, stream>>>(G16,
            PT + (size_t)par*PT_B, PT + (size_t)(par^1)*PT_B,
            Wt + 2*WT_SET, 0, Weff + 2*WSET, 0, Mw + 2*M_SET, 0, tvt,
            ZR, Hdec, nullptr, nullptr, nullptr, nullptr, nullptr);
        par ^= 1;
        k_fstep<1,1><<<dim3(163,1), 512, 0, stream>>>(G16,
            PT + (size_t)par*PT_B, PT + (size_t)(par^1)*PT_B,
            Wt + 2*WT_SET, 0, Weff + 2*WSET, 0, Mw + 2*M_SET, 0, tvt,
            ZR, Hdec, nullptr, nullptr, W_fc, b_fc, ys + (size_t)t*NB*3);
        par ^= 1;
    }

    k_out<<<(BB*3*NN*12 + 255)/256, 256, 0, stream>>>(ys, (float*)d_out);
}